// Round 3
// baseline (286.607 us; speedup 1.0000x reference)
//
#include <hip/hip_runtime.h>
#include <hip/hip_bf16.h>

typedef __attribute__((ext_vector_type(8))) __bf16 bf16x8;
typedef __attribute__((ext_vector_type(4))) __bf16 bf16x4;
typedef __attribute__((ext_vector_type(4))) float f32x4;

#define DIN 1024
#define DOUT 1024
#define BB 4
#define SS 4096
#define MROWS (BB*SS)   /* 16384 */
#define POOLN 5
#define RR 8
#define NTASKS 5
#define TOPKK 3

// ---------------- K1: colsum + f32->bf16 convert (copy-shaped, full occupancy) ----
// 2048 blocks x 256 threads = 8 blocks/CU (the 2048-thread/CU cap) -> 32 waves/CU.
// Grid-stride over 4M float4, 8 iters/thread, stride 524288 float4 (== 0 mod 256)
// so each thread's 4 columns are constant -> 4 reg accumulators + 4 atomics at end.
__global__ __launch_bounds__(256) void k1_colsum_cvt(const float* __restrict__ in,
                                                     __bf16* __restrict__ inB,
                                                     float* __restrict__ colsum) {
    const int idx0 = blockIdx.x * 256 + threadIdx.x;     // 0..524287
    const float4* __restrict__ inv = (const float4*)in;
    bf16x4* __restrict__ outv = (bf16x4*)inB;

    float s0 = 0.f, s1 = 0.f, s2 = 0.f, s3 = 0.f;
    size_t idx = idx0;
    float4 cur = inv[idx];
#pragma unroll
    for (int it = 0; it < 8; ++it) {
        float4 nxt = cur;
        if (it < 7) nxt = inv[idx + 524288];             // prefetch next before use
        s0 += cur.x; s1 += cur.y; s2 += cur.z; s3 += cur.w;
        bf16x4 b = { (__bf16)cur.x, (__bf16)cur.y, (__bf16)cur.z, (__bf16)cur.w };
        outv[idx] = b;
        cur = nxt;
        idx += 524288;
    }
    const int c0 = (idx0 * 4) & (DIN - 1);
    atomicAdd(&colsum[c0 + 0], s0);
    atomicAdd(&colsum[c0 + 1], s1);
    atomicAdd(&colsum[c0 + 2], s2);
    atomicAdd(&colsum[c0 + 3], s3);
}

// ---------------- K2: omegas -> top-k -> softmax gate ----------------
__global__ void k2_gate(const float* __restrict__ colsum,
                        const float* __restrict__ lroute,
                        const int* __restrict__ task_id_p,
                        float* __restrict__ gate, int* __restrict__ gidx) {
    const int l = threadIdx.x;  // 64 lanes
    float part[POOLN] = {0.f, 0.f, 0.f, 0.f, 0.f};
    for (int d = l; d < DIN; d += 64) {
        const float cs = colsum[d] * (1.0f / (float)MROWS);
        const float* rp = &lroute[(size_t)1 * DIN * POOLN + (size_t)d * POOLN];
#pragma unroll
        for (int p = 0; p < POOLN; ++p) part[p] += cs * rp[p];
    }
#pragma unroll
    for (int p = 0; p < POOLN; ++p) {
        float v = part[p];
        for (int off = 32; off; off >>= 1) v += __shfl_down(v, off);
        part[p] = v;
    }
    if (l == 0) {
        int tid = *task_id_p;
        if (tid > NTASKS) tid = NTASKS;
        int L = tid < (POOLN - 1) ? tid : (POOLN - 1);   // slice [1:tid+1] clamps
        int k = tid < TOPKK ? tid : TOPKK;
        float sl[POOLN];
        for (int j = 0; j < L; ++j) sl[j] = part[1 + j];
        float G[TOPKK]; int I[TOPKK];
        int used = 0;
        for (int j = 0; j < k; ++j) {
            int best = -1; float bv = 0.f;
            for (int i2 = 0; i2 < L; ++i2) {
                if (used & (1 << i2)) continue;
                if (best < 0 || sl[i2] > bv) { bv = sl[i2]; best = i2; }
            }
            used |= 1 << best; G[j] = bv; I[j] = best;
        }
        if (k > 0) {
            float m = G[0];           // descending -> max first
            float e[TOPKK]; float se = 0.f;
            for (int j = 0; j < k; ++j) { e[j] = expf(G[j] - m); se += e[j]; }
            for (int j = 0; j < k; ++j) { gate[j] = e[j] / se; gidx[j] = I[j]; }
        }
        for (int j = k; j < TOPKK; ++j) { gate[j] = 0.f; gidx[j] = 0; }
    }
}

// ---------------- K3: build two bf16 B^T weight matrices ----------------
// Wb0[o][d] = bf16(W[o][d]);  Wb1[o][d] = bf16(W[o][d] + Dw[d][o])
// Dw[d][o] = sum_j gate_j * sum_r down[I_j][d][r] * up[I_j][r][o]
__global__ __launch_bounds__(256) void k3_weights(const float* __restrict__ W,
                                                  const float* __restrict__ ldown,
                                                  const float* __restrict__ lup,
                                                  const float* __restrict__ gate,
                                                  const int* __restrict__ gidx,
                                                  __bf16* __restrict__ Wb0,
                                                  __bf16* __restrict__ Wb1) {
    const int o = blockIdx.x;
    const int t = threadIdx.x;
    float c[TOPKK][RR];
#pragma unroll
    for (int j = 0; j < TOPKK; ++j) {
        const float g = gate[j];
        const int   p = gidx[j];
#pragma unroll
        for (int r = 0; r < RR; ++r)
            c[j][r] = g * lup[(size_t)p * RR * DOUT + (size_t)r * DOUT + o];
    }
    const int d0 = t * 4;
    const float4 wv = *(const float4*)&W[(size_t)o * DIN + d0];
    float outv[4] = { wv.x, wv.y, wv.z, wv.w };
    float dwv[4]  = { 0.f, 0.f, 0.f, 0.f };
#pragma unroll
    for (int j = 0; j < TOPKK; ++j) {
        const int p = gidx[j];
#pragma unroll
        for (int dd = 0; dd < 4; ++dd) {
            const float4 da = *(const float4*)&ldown[(size_t)p * DIN * RR + (size_t)(d0 + dd) * RR];
            const float4 db = *(const float4*)&ldown[(size_t)p * DIN * RR + (size_t)(d0 + dd) * RR + 4];
            dwv[dd] += da.x * c[j][0] + da.y * c[j][1] + da.z * c[j][2] + da.w * c[j][3]
                     + db.x * c[j][4] + db.y * c[j][5] + db.z * c[j][6] + db.w * c[j][7];
        }
    }
    bf16x4 b0 = { (__bf16)outv[0], (__bf16)outv[1], (__bf16)outv[2], (__bf16)outv[3] };
    bf16x4 b1 = { (__bf16)(outv[0] + dwv[0]), (__bf16)(outv[1] + dwv[1]),
                  (__bf16)(outv[2] + dwv[2]), (__bf16)(outv[3] + dwv[3]) };
    *(bf16x4*)&Wb0[(size_t)o * DIN + d0] = b0;
    *(bf16x4*)&Wb1[(size_t)o * DIN + d0] = b1;
}

// ---------------- K4: 128x128 bf16 MFMA GEMM (B^T layout) ----------------
// C[m][n] = sum_k A[m][k] * Bt[n][k];  Bt = Wb0 for tm<64, Wb1 for tm>=64.
__global__ __launch_bounds__(256) void k4_gemm(const __bf16* __restrict__ A,
                                               const __bf16* __restrict__ B0,
                                               const __bf16* __restrict__ B1,
                                               float* __restrict__ C) {
    __shared__ ushort As[128 * 64];
    __shared__ ushort Bs[128 * 64];
    const int tn = blockIdx.x;   // 0..7
    const int tm = blockIdx.y;   // 0..127
    const __bf16* __restrict__ Bt = (tm >= 64) ? B1 : B0;
    const int lane = threadIdx.x & 63;
    const int wid  = threadIdx.x >> 6;
    const int wm = wid >> 1, wn = wid & 1;

    // staging geometry: chunk c = wid*4+i covers LDS rows c*8..c*8+7, full BK=64.
    // lane -> row c*8 + (lane>>3), 16B k-chunk (lane&7); pre-swizzle global source
    // so that logical chunk lk = (lane&7) ^ (row&7) lands at linear LDS slot.
    const int lr = lane >> 3;
    const int lk = (lane & 7) ^ lr;

    f32x4 acc[4][4];
#pragma unroll
    for (int i = 0; i < 4; ++i)
#pragma unroll
        for (int j = 0; j < 4; ++j) acc[i][j] = (f32x4){0.f, 0.f, 0.f, 0.f};

    const size_t abase = (size_t)tm * 128 * 1024;
    const size_t bbase = (size_t)tn * 128 * 1024;

    auto stage = [&](int kt) {
#pragma unroll
        for (int i = 0; i < 4; ++i) {
            const int c   = wid * 4 + i;
            const int row = c * 8 + lr;
            const __bf16* ga = A  + abase + (size_t)row * 1024 + (size_t)kt * 64 + lk * 8;
            const __bf16* gb = Bt + bbase + (size_t)row * 1024 + (size_t)kt * 64 + lk * 8;
            __builtin_amdgcn_global_load_lds((const __attribute__((address_space(1))) void*)ga,
                                             (__attribute__((address_space(3))) void*)&As[c * 512],
                                             16, 0, 0);
            __builtin_amdgcn_global_load_lds((const __attribute__((address_space(1))) void*)gb,
                                             (__attribute__((address_space(3))) void*)&Bs[c * 512],
                                             16, 0, 0);
        }
    };

    stage(0);
#pragma unroll 1
    for (int kt = 0; kt < 16; ++kt) {
        __syncthreads();   // compiler emits vmcnt(0) drain before barrier
#pragma unroll
        for (int ks = 0; ks < 2; ++ks) {
            bf16x8 af[4], bfr[4];
            const int chb = (ks * 4 + (lane >> 4)) ^ (lane & 7);  // swizzled 16B chunk
#pragma unroll
            for (int mi = 0; mi < 4; ++mi) {
                const int row = wm * 64 + mi * 16 + (lane & 15);
                af[mi] = *(const bf16x8*)&As[row * 64 + chb * 8];
            }
#pragma unroll
            for (int ni = 0; ni < 4; ++ni) {
                const int row = wn * 64 + ni * 16 + (lane & 15);
                bfr[ni] = *(const bf16x8*)&Bs[row * 64 + chb * 8];
            }
#pragma unroll
            for (int mi = 0; mi < 4; ++mi)
#pragma unroll
                for (int ni = 0; ni < 4; ++ni)
                    acc[mi][ni] = __builtin_amdgcn_mfma_f32_16x16x32_bf16(
                        af[mi], bfr[ni], acc[mi][ni], 0, 0, 0);
        }
        __syncthreads();
        if (kt < 15) stage(kt + 1);
    }

    // epilogue: D col = lane&15, row = (lane>>4)*4 + r
#pragma unroll
    for (int mi = 0; mi < 4; ++mi) {
#pragma unroll
        for (int r = 0; r < 4; ++r) {
            const int grow = tm * 128 + wm * 64 + mi * 16 + (lane >> 4) * 4 + r;
            float* cp = C + (size_t)grow * 1024 + tn * 128 + wn * 64 + (lane & 15);
#pragma unroll
            for (int ni = 0; ni < 4; ++ni) cp[ni * 16] = acc[mi][ni][r];
        }
    }
}

extern "C" void kernel_launch(void* const* d_in, const int* in_sizes, int n_in,
                              void* d_out, int out_size, void* d_ws, size_t ws_size,
                              hipStream_t stream) {
    const float* in     = (const float*)d_in[0];
    const float* W      = (const float*)d_in[1];
    const float* ldown  = (const float*)d_in[2];
    const float* lup    = (const float*)d_in[3];
    const float* lroute = (const float*)d_in[4];
    const int*   taskid = (const int*)d_in[5];
    float* out = (float*)d_out;

    // workspace carve (needs ~37.6 MB)
    __bf16* inB   = (__bf16*)d_ws;                              // 16384*1024*2 B
    __bf16* Wb0   = inB + (size_t)MROWS * DIN;                  // 2 MB
    __bf16* Wb1   = Wb0 + (size_t)DOUT * DIN;                   // 2 MB
    float*  colsum= (float*)(Wb1 + (size_t)DOUT * DIN);         // 4 KB
    float*  gate  = colsum + DIN;
    int*    gidx  = (int*)(gate + TOPKK);

    hipMemsetAsync(colsum, 0, DIN * sizeof(float), stream);
    k1_colsum_cvt<<<2048, 256, 0, stream>>>(in, inB, colsum);
    k2_gate<<<1, 64, 0, stream>>>(colsum, lroute, taskid, gate, gidx);
    k3_weights<<<1024, 256, 0, stream>>>(W, ldown, lup, gate, gidx, Wb0, Wb1);
    k4_gemm<<<dim3(8, 128), 256, 0, stream>>>(inB, Wb0, Wb1, out);
}

// Round 4
// 112.622 us; speedup vs baseline: 2.5449x; 2.5449x over previous
//
#include <hip/hip_runtime.h>
#include <hip/hip_bf16.h>

typedef __attribute__((ext_vector_type(8))) __bf16 bf16x8;
typedef __attribute__((ext_vector_type(4))) __bf16 bf16x4;
typedef __attribute__((ext_vector_type(4))) float f32x4;

#define DIN 1024
#define DOUT 1024
#define BB 4
#define SS 4096
#define MROWS (BB*SS)   /* 16384 */
#define POOLN 5
#define RR 8
#define NTASKS 5
#define TOPKK 3

// ---------------- K1a: streaming colsum-partials + f32->bf16 convert ----------
// 2048 blocks x 256 threads, grid-stride 8 iters, stride 524288 float4 (==0 mod 256)
// -> each thread's 4 columns constant; block's 256 threads cover all 1024 columns
// exactly once. NO atomics: per-block partials written coalesced to `partial`.
__global__ __launch_bounds__(256) void k1a_stream(const float* __restrict__ in,
                                                  __bf16* __restrict__ inB,
                                                  float* __restrict__ partial) {
    const int t = threadIdx.x;
    const int b = blockIdx.x;
    const int idx0 = b * 256 + t;                        // 0..524287
    const float4* __restrict__ inv = (const float4*)in;
    bf16x4* __restrict__ outv = (bf16x4*)inB;

    float s0 = 0.f, s1 = 0.f, s2 = 0.f, s3 = 0.f;
    size_t idx = idx0;
    float4 cur = inv[idx];
#pragma unroll
    for (int it = 0; it < 8; ++it) {
        float4 nxt = cur;
        if (it < 7) nxt = inv[idx + 524288];             // prefetch next before use
        s0 += cur.x; s1 += cur.y; s2 += cur.z; s3 += cur.w;
        bf16x4 bb = { (__bf16)cur.x, (__bf16)cur.y, (__bf16)cur.z, (__bf16)cur.w };
        outv[idx] = bb;
        cur = nxt;
        idx += 524288;
    }
    float4 p = { s0, s1, s2, s3 };
    *(float4*)&partial[(size_t)b * DIN + t * 4] = p;     // coalesced float4 store
}

// ---------------- K1b: reduce partial[2048][1024] -> colsum[1024] -------------
// 32 blocks x 256 threads: thread (g,c) sums 256 partial rows of column c.
// Reads coalesced (consecutive lanes -> consecutive columns). 8 atomics/address.
__global__ __launch_bounds__(256) void k1b_reduce(const float* __restrict__ partial,
                                                  float* __restrict__ colsum) {
    const int tid = blockIdx.x * 256 + threadIdx.x;      // 0..8191
    const int c = tid & (DIN - 1);
    const int g = tid >> 10;                             // 0..7
    float s = 0.f;
    const int b0 = g * 256;
#pragma unroll 8
    for (int b = b0; b < b0 + 256; ++b)
        s += partial[(size_t)b * DIN + c];
    atomicAdd(&colsum[c], s);
}

// ---------------- K2: omegas -> top-k -> softmax gate ----------------
__global__ void k2_gate(const float* __restrict__ colsum,
                        const float* __restrict__ lroute,
                        const int* __restrict__ task_id_p,
                        float* __restrict__ gate, int* __restrict__ gidx) {
    const int l = threadIdx.x;  // 64 lanes
    float part[POOLN] = {0.f, 0.f, 0.f, 0.f, 0.f};
    for (int d = l; d < DIN; d += 64) {
        const float cs = colsum[d] * (1.0f / (float)MROWS);
        const float* rp = &lroute[(size_t)1 * DIN * POOLN + (size_t)d * POOLN];
#pragma unroll
        for (int p = 0; p < POOLN; ++p) part[p] += cs * rp[p];
    }
#pragma unroll
    for (int p = 0; p < POOLN; ++p) {
        float v = part[p];
        for (int off = 32; off; off >>= 1) v += __shfl_down(v, off);
        part[p] = v;
    }
    if (l == 0) {
        int tid = *task_id_p;
        if (tid > NTASKS) tid = NTASKS;
        int L = tid < (POOLN - 1) ? tid : (POOLN - 1);   // slice [1:tid+1] clamps
        int k = tid < TOPKK ? tid : TOPKK;
        float sl[POOLN];
        for (int j = 0; j < L; ++j) sl[j] = part[1 + j];
        float G[TOPKK]; int I[TOPKK];
        int used = 0;
        for (int j = 0; j < k; ++j) {
            int best = -1; float bv = 0.f;
            for (int i2 = 0; i2 < L; ++i2) {
                if (used & (1 << i2)) continue;
                if (best < 0 || sl[i2] > bv) { bv = sl[i2]; best = i2; }
            }
            used |= 1 << best; G[j] = bv; I[j] = best;
        }
        if (k > 0) {
            float m = G[0];           // descending -> max first
            float e[TOPKK]; float se = 0.f;
            for (int j = 0; j < k; ++j) { e[j] = expf(G[j] - m); se += e[j]; }
            for (int j = 0; j < k; ++j) { gate[j] = e[j] / se; gidx[j] = I[j]; }
        }
        for (int j = k; j < TOPKK; ++j) { gate[j] = 0.f; gidx[j] = 0; }
    }
}

// ---------------- K3: build two bf16 B^T weight matrices ----------------
__global__ __launch_bounds__(256) void k3_weights(const float* __restrict__ W,
                                                  const float* __restrict__ ldown,
                                                  const float* __restrict__ lup,
                                                  const float* __restrict__ gate,
                                                  const int* __restrict__ gidx,
                                                  __bf16* __restrict__ Wb0,
                                                  __bf16* __restrict__ Wb1) {
    const int o = blockIdx.x;
    const int t = threadIdx.x;
    float c[TOPKK][RR];
#pragma unroll
    for (int j = 0; j < TOPKK; ++j) {
        const float g = gate[j];
        const int   p = gidx[j];
#pragma unroll
        for (int r = 0; r < RR; ++r)
            c[j][r] = g * lup[(size_t)p * RR * DOUT + (size_t)r * DOUT + o];
    }
    const int d0 = t * 4;
    const float4 wv = *(const float4*)&W[(size_t)o * DIN + d0];
    float outv[4] = { wv.x, wv.y, wv.z, wv.w };
    float dwv[4]  = { 0.f, 0.f, 0.f, 0.f };
#pragma unroll
    for (int j = 0; j < TOPKK; ++j) {
        const int p = gidx[j];
#pragma unroll
        for (int dd = 0; dd < 4; ++dd) {
            const float4 da = *(const float4*)&ldown[(size_t)p * DIN * RR + (size_t)(d0 + dd) * RR];
            const float4 db = *(const float4*)&ldown[(size_t)p * DIN * RR + (size_t)(d0 + dd) * RR + 4];
            dwv[dd] += da.x * c[j][0] + da.y * c[j][1] + da.z * c[j][2] + da.w * c[j][3]
                     + db.x * c[j][4] + db.y * c[j][5] + db.z * c[j][6] + db.w * c[j][7];
        }
    }
    bf16x4 b0 = { (__bf16)outv[0], (__bf16)outv[1], (__bf16)outv[2], (__bf16)outv[3] };
    bf16x4 b1 = { (__bf16)(outv[0] + dwv[0]), (__bf16)(outv[1] + dwv[1]),
                  (__bf16)(outv[2] + dwv[2]), (__bf16)(outv[3] + dwv[3]) };
    *(bf16x4*)&Wb0[(size_t)o * DIN + d0] = b0;
    *(bf16x4*)&Wb1[(size_t)o * DIN + d0] = b1;
}

// ---------------- K4: 128x128 bf16 MFMA GEMM (B^T layout) ----------------
__global__ __launch_bounds__(256) void k4_gemm(const __bf16* __restrict__ A,
                                               const __bf16* __restrict__ B0,
                                               const __bf16* __restrict__ B1,
                                               float* __restrict__ C) {
    __shared__ ushort As[128 * 64];
    __shared__ ushort Bs[128 * 64];
    const int tn = blockIdx.x;   // 0..7
    const int tm = blockIdx.y;   // 0..127
    const __bf16* __restrict__ Bt = (tm >= 64) ? B1 : B0;
    const int lane = threadIdx.x & 63;
    const int wid  = threadIdx.x >> 6;
    const int wm = wid >> 1, wn = wid & 1;

    const int lr = lane >> 3;
    const int lk = (lane & 7) ^ lr;

    f32x4 acc[4][4];
#pragma unroll
    for (int i = 0; i < 4; ++i)
#pragma unroll
        for (int j = 0; j < 4; ++j) acc[i][j] = (f32x4){0.f, 0.f, 0.f, 0.f};

    const size_t abase = (size_t)tm * 128 * 1024;
    const size_t bbase = (size_t)tn * 128 * 1024;

    auto stage = [&](int kt) {
#pragma unroll
        for (int i = 0; i < 4; ++i) {
            const int c   = wid * 4 + i;
            const int row = c * 8 + lr;
            const __bf16* ga = A  + abase + (size_t)row * 1024 + (size_t)kt * 64 + lk * 8;
            const __bf16* gb = Bt + bbase + (size_t)row * 1024 + (size_t)kt * 64 + lk * 8;
            __builtin_amdgcn_global_load_lds((const __attribute__((address_space(1))) void*)ga,
                                             (__attribute__((address_space(3))) void*)&As[c * 512],
                                             16, 0, 0);
            __builtin_amdgcn_global_load_lds((const __attribute__((address_space(1))) void*)gb,
                                             (__attribute__((address_space(3))) void*)&Bs[c * 512],
                                             16, 0, 0);
        }
    };

    stage(0);
#pragma unroll 1
    for (int kt = 0; kt < 16; ++kt) {
        __syncthreads();
#pragma unroll
        for (int ks = 0; ks < 2; ++ks) {
            bf16x8 af[4], bfr[4];
            const int chb = (ks * 4 + (lane >> 4)) ^ (lane & 7);  // swizzled 16B chunk
#pragma unroll
            for (int mi = 0; mi < 4; ++mi) {
                const int row = wm * 64 + mi * 16 + (lane & 15);
                af[mi] = *(const bf16x8*)&As[row * 64 + chb * 8];
            }
#pragma unroll
            for (int ni = 0; ni < 4; ++ni) {
                const int row = wn * 64 + ni * 16 + (lane & 15);
                bfr[ni] = *(const bf16x8*)&Bs[row * 64 + chb * 8];
            }
#pragma unroll
            for (int mi = 0; mi < 4; ++mi)
#pragma unroll
                for (int ni = 0; ni < 4; ++ni)
                    acc[mi][ni] = __builtin_amdgcn_mfma_f32_16x16x32_bf16(
                        af[mi], bfr[ni], acc[mi][ni], 0, 0, 0);
        }
        __syncthreads();
        if (kt < 15) stage(kt + 1);
    }

#pragma unroll
    for (int mi = 0; mi < 4; ++mi) {
#pragma unroll
        for (int r = 0; r < 4; ++r) {
            const int grow = tm * 128 + wm * 64 + mi * 16 + (lane >> 4) * 4 + r;
            float* cp = C + (size_t)grow * 1024 + tn * 128 + wn * 64 + (lane & 15);
#pragma unroll
            for (int ni = 0; ni < 4; ++ni) cp[ni * 16] = acc[mi][ni][r];
        }
    }
}

extern "C" void kernel_launch(void* const* d_in, const int* in_sizes, int n_in,
                              void* d_out, int out_size, void* d_ws, size_t ws_size,
                              hipStream_t stream) {
    const float* in     = (const float*)d_in[0];
    const float* W      = (const float*)d_in[1];
    const float* ldown  = (const float*)d_in[2];
    const float* lup    = (const float*)d_in[3];
    const float* lroute = (const float*)d_in[4];
    const int*   taskid = (const int*)d_in[5];
    float* out = (float*)d_out;

    // workspace carve (~36.6 MB)
    __bf16* inB   = (__bf16*)d_ws;                              // 32 MB
    __bf16* Wb0   = inB + (size_t)MROWS * DIN;                  // 2 MB
    __bf16* Wb1   = Wb0 + (size_t)DOUT * DIN;                   // 2 MB
    float*  colsum= (float*)(Wb1 + (size_t)DOUT * DIN);         // 4 KB
    float*  gate  = colsum + DIN;
    int*    gidx  = (int*)(gate + TOPKK);

    // partial colsums live in d_out (8 MB of its 64 MB) — k4 fully overwrites
    // d_out afterwards, so this is deterministic and costs no workspace.
    float* partial = out;

    hipMemsetAsync(colsum, 0, DIN * sizeof(float), stream);
    k1a_stream<<<2048, 256, 0, stream>>>(in, inB, partial);
    k1b_reduce<<<32, 256, 0, stream>>>(partial, colsum);
    k2_gate<<<1, 64, 0, stream>>>(colsum, lroute, taskid, gate, gidx);
    k3_weights<<<1024, 256, 0, stream>>>(W, ldown, lup, gate, gidx, Wb0, Wb1);
    k4_gemm<<<dim3(8, 128), 256, 0, stream>>>(inB, Wb0, Wb1, out);
}

// Round 5
// 105.490 us; speedup vs baseline: 2.7169x; 1.0676x over previous
//
#include <hip/hip_runtime.h>
#include <hip/hip_bf16.h>

typedef __attribute__((ext_vector_type(8))) __bf16 bf16x8;
typedef __attribute__((ext_vector_type(4))) __bf16 bf16x4;
typedef __attribute__((ext_vector_type(4))) float f32x4;

#define DIN 1024
#define DOUT 1024
#define BB 4
#define SS 4096
#define MROWS (BB*SS)   /* 16384 */
#define POOLN 5
#define RR 8
#define NTASKS 5
#define TOPKK 3

// ---------------- K1a: streaming colsum-partials + f32->bf16 convert ----------
__global__ __launch_bounds__(256) void k1a_stream(const float* __restrict__ in,
                                                  __bf16* __restrict__ inB,
                                                  float* __restrict__ partial) {
    const int t = threadIdx.x;
    const int b = blockIdx.x;
    const int idx0 = b * 256 + t;                        // 0..524287
    const float4* __restrict__ inv = (const float4*)in;
    bf16x4* __restrict__ outv = (bf16x4*)inB;

    float s0 = 0.f, s1 = 0.f, s2 = 0.f, s3 = 0.f;
    size_t idx = idx0;
    float4 cur = inv[idx];
#pragma unroll
    for (int it = 0; it < 8; ++it) {
        float4 nxt = cur;
        if (it < 7) nxt = inv[idx + 524288];             // prefetch next before use
        s0 += cur.x; s1 += cur.y; s2 += cur.z; s3 += cur.w;
        bf16x4 bb = { (__bf16)cur.x, (__bf16)cur.y, (__bf16)cur.z, (__bf16)cur.w };
        outv[idx] = bb;
        cur = nxt;
        idx += 524288;
    }
    float4 p = { s0, s1, s2, s3 };
    *(float4*)&partial[(size_t)b * DIN + t * 4] = p;     // coalesced float4 store
}

// ---------------- K1b: reduce partial[2048][1024] -> colsum[1024] -------------
__global__ __launch_bounds__(256) void k1b_reduce(const float* __restrict__ partial,
                                                  float* __restrict__ colsum) {
    const int tid = blockIdx.x * 256 + threadIdx.x;      // 0..8191
    const int c = tid & (DIN - 1);
    const int g = tid >> 10;                             // 0..7
    float s = 0.f;
    const int b0 = g * 256;
#pragma unroll 8
    for (int b = b0; b < b0 + 256; ++b)
        s += partial[(size_t)b * DIN + c];
    atomicAdd(&colsum[c], s);
}

// ---------------- K2: omegas -> top-k -> softmax gate ----------------
__global__ void k2_gate(const float* __restrict__ colsum,
                        const float* __restrict__ lroute,
                        const int* __restrict__ task_id_p,
                        float* __restrict__ gate, int* __restrict__ gidx) {
    const int l = threadIdx.x;  // 64 lanes
    float part[POOLN] = {0.f, 0.f, 0.f, 0.f, 0.f};
    for (int d = l; d < DIN; d += 64) {
        const float cs = colsum[d] * (1.0f / (float)MROWS);
        const float* rp = &lroute[(size_t)1 * DIN * POOLN + (size_t)d * POOLN];
#pragma unroll
        for (int p = 0; p < POOLN; ++p) part[p] += cs * rp[p];
    }
#pragma unroll
    for (int p = 0; p < POOLN; ++p) {
        float v = part[p];
        for (int off = 32; off; off >>= 1) v += __shfl_down(v, off);
        part[p] = v;
    }
    if (l == 0) {
        int tid = *task_id_p;
        if (tid > NTASKS) tid = NTASKS;
        int L = tid < (POOLN - 1) ? tid : (POOLN - 1);   // slice [1:tid+1] clamps
        int k = tid < TOPKK ? tid : TOPKK;
        float sl[POOLN];
        for (int j = 0; j < L; ++j) sl[j] = part[1 + j];
        float G[TOPKK]; int I[TOPKK];
        int used = 0;
        for (int j = 0; j < k; ++j) {
            int best = -1; float bv = 0.f;
            for (int i2 = 0; i2 < L; ++i2) {
                if (used & (1 << i2)) continue;
                if (best < 0 || sl[i2] > bv) { bv = sl[i2]; best = i2; }
            }
            used |= 1 << best; G[j] = bv; I[j] = best;
        }
        if (k > 0) {
            float m = G[0];           // descending -> max first
            float e[TOPKK]; float se = 0.f;
            for (int j = 0; j < k; ++j) { e[j] = expf(G[j] - m); se += e[j]; }
            for (int j = 0; j < k; ++j) { gate[j] = e[j] / se; gidx[j] = I[j]; }
        }
        for (int j = k; j < TOPKK; ++j) { gate[j] = 0.f; gidx[j] = 0; }
    }
}

// ---------------- K3: build two bf16 B^T weight matrices ----------------
__global__ __launch_bounds__(256) void k3_weights(const float* __restrict__ W,
                                                  const float* __restrict__ ldown,
                                                  const float* __restrict__ lup,
                                                  const float* __restrict__ gate,
                                                  const int* __restrict__ gidx,
                                                  __bf16* __restrict__ Wb0,
                                                  __bf16* __restrict__ Wb1) {
    const int o = blockIdx.x;
    const int t = threadIdx.x;
    float c[TOPKK][RR];
#pragma unroll
    for (int j = 0; j < TOPKK; ++j) {
        const float g = gate[j];
        const int   p = gidx[j];
#pragma unroll
        for (int r = 0; r < RR; ++r)
            c[j][r] = g * lup[(size_t)p * RR * DOUT + (size_t)r * DOUT + o];
    }
    const int d0 = t * 4;
    const float4 wv = *(const float4*)&W[(size_t)o * DIN + d0];
    float outv[4] = { wv.x, wv.y, wv.z, wv.w };
    float dwv[4]  = { 0.f, 0.f, 0.f, 0.f };
#pragma unroll
    for (int j = 0; j < TOPKK; ++j) {
        const int p = gidx[j];
#pragma unroll
        for (int dd = 0; dd < 4; ++dd) {
            const float4 da = *(const float4*)&ldown[(size_t)p * DIN * RR + (size_t)(d0 + dd) * RR];
            const float4 db = *(const float4*)&ldown[(size_t)p * DIN * RR + (size_t)(d0 + dd) * RR + 4];
            dwv[dd] += da.x * c[j][0] + da.y * c[j][1] + da.z * c[j][2] + da.w * c[j][3]
                     + db.x * c[j][4] + db.y * c[j][5] + db.z * c[j][6] + db.w * c[j][7];
        }
    }
    bf16x4 b0 = { (__bf16)outv[0], (__bf16)outv[1], (__bf16)outv[2], (__bf16)outv[3] };
    bf16x4 b1 = { (__bf16)(outv[0] + dwv[0]), (__bf16)(outv[1] + dwv[1]),
                  (__bf16)(outv[2] + dwv[2]), (__bf16)(outv[3] + dwv[3]) };
    *(bf16x4*)&Wb0[(size_t)o * DIN + d0] = b0;
    *(bf16x4*)&Wb1[(size_t)o * DIN + d0] = b1;
}

// ---------------- K4: 128x128 bf16 MFMA GEMM, XCD-local A-tile reuse ----------
// Linear grid of 1024 blocks; bid -> (tm,tn) such that all 8 tn-blocks of one
// tm-tile share bid%8 (= same XCD under round-robin dispatch) and run
// concurrently -> A-tile fetched from HBM once per XCD, L2-served 7x.
__global__ __launch_bounds__(256) void k4_gemm(const __bf16* __restrict__ A,
                                               const __bf16* __restrict__ B0,
                                               const __bf16* __restrict__ B1,
                                               float* __restrict__ C) {
    __shared__ ushort As[128 * 64];
    __shared__ ushort Bs[128 * 64];
    const int bid = blockIdx.x;            // 0..1023
    const int tn  = (bid >> 3) & 7;        // 0..7
    const int tm  = (bid & 7) + 8 * (bid >> 6);   // 0..127, tm%8 == bid%8
    const __hip_bfloat16* __restrict__ dummy = nullptr; (void)dummy;
    const __bf16* __restrict__ Bt = (tm >= 64) ? B1 : B0;
    const int lane = threadIdx.x & 63;
    const int wid  = threadIdx.x >> 6;
    const int wm = wid >> 1, wn = wid & 1;

    const int lr = lane >> 3;
    const int lk = (lane & 7) ^ lr;

    f32x4 acc[4][4];
#pragma unroll
    for (int i = 0; i < 4; ++i)
#pragma unroll
        for (int j = 0; j < 4; ++j) acc[i][j] = (f32x4){0.f, 0.f, 0.f, 0.f};

    const size_t abase = (size_t)tm * 128 * 1024;
    const size_t bbase = (size_t)tn * 128 * 1024;

    auto stage = [&](int kt) {
#pragma unroll
        for (int i = 0; i < 4; ++i) {
            const int c   = wid * 4 + i;
            const int row = c * 8 + lr;
            const __bf16* ga = A  + abase + (size_t)row * 1024 + (size_t)kt * 64 + lk * 8;
            const __bf16* gb = Bt + bbase + (size_t)row * 1024 + (size_t)kt * 64 + lk * 8;
            __builtin_amdgcn_global_load_lds((const __attribute__((address_space(1))) void*)ga,
                                             (__attribute__((address_space(3))) void*)&As[c * 512],
                                             16, 0, 0);
            __builtin_amdgcn_global_load_lds((const __attribute__((address_space(1))) void*)gb,
                                             (__attribute__((address_space(3))) void*)&Bs[c * 512],
                                             16, 0, 0);
        }
    };

    stage(0);
#pragma unroll 1
    for (int kt = 0; kt < 16; ++kt) {
        __syncthreads();
#pragma unroll
        for (int ks = 0; ks < 2; ++ks) {
            bf16x8 af[4], bfr[4];
            const int chb = (ks * 4 + (lane >> 4)) ^ (lane & 7);  // swizzled 16B chunk
#pragma unroll
            for (int mi = 0; mi < 4; ++mi) {
                const int row = wm * 64 + mi * 16 + (lane & 15);
                af[mi] = *(const bf16x8*)&As[row * 64 + chb * 8];
            }
#pragma unroll
            for (int ni = 0; ni < 4; ++ni) {
                const int row = wn * 64 + ni * 16 + (lane & 15);
                bfr[ni] = *(const bf16x8*)&Bs[row * 64 + chb * 8];
            }
#pragma unroll
            for (int mi = 0; mi < 4; ++mi)
#pragma unroll
                for (int ni = 0; ni < 4; ++ni)
                    acc[mi][ni] = __builtin_amdgcn_mfma_f32_16x16x32_bf16(
                        af[mi], bfr[ni], acc[mi][ni], 0, 0, 0);
        }
        __syncthreads();
        if (kt < 15) stage(kt + 1);
    }

#pragma unroll
    for (int mi = 0; mi < 4; ++mi) {
#pragma unroll
        for (int r = 0; r < 4; ++r) {
            const int grow = tm * 128 + wm * 64 + mi * 16 + (lane >> 4) * 4 + r;
            float* cp = C + (size_t)grow * 1024 + tn * 128 + wn * 64 + (lane & 15);
#pragma unroll
            for (int ni = 0; ni < 4; ++ni) cp[ni * 16] = acc[mi][ni][r];
        }
    }
}

extern "C" void kernel_launch(void* const* d_in, const int* in_sizes, int n_in,
                              void* d_out, int out_size, void* d_ws, size_t ws_size,
                              hipStream_t stream) {
    const float* in     = (const float*)d_in[0];
    const float* W      = (const float*)d_in[1];
    const float* ldown  = (const float*)d_in[2];
    const float* lup    = (const float*)d_in[3];
    const float* lroute = (const float*)d_in[4];
    const int*   taskid = (const int*)d_in[5];
    float* out = (float*)d_out;

    // workspace carve (~36.6 MB)
    __bf16* inB   = (__bf16*)d_ws;                              // 32 MB
    __bf16* Wb0   = inB + (size_t)MROWS * DIN;                  // 2 MB
    __bf16* Wb1   = Wb0 + (size_t)DOUT * DIN;                   // 2 MB
    float*  colsum= (float*)(Wb1 + (size_t)DOUT * DIN);         // 4 KB
    float*  gate  = colsum + DIN;
    int*    gidx  = (int*)(gate + TOPKK);

    // partial colsums live in d_out (8 MB of its 64 MB) — k4 fully overwrites
    // d_out afterwards, so this is deterministic and costs no workspace.
    float* partial = out;

    hipMemsetAsync(colsum, 0, DIN * sizeof(float), stream);
    k1a_stream<<<2048, 256, 0, stream>>>(in, inB, partial);
    k1b_reduce<<<32, 256, 0, stream>>>(partial, colsum);
    k2_gate<<<1, 64, 0, stream>>>(colsum, lroute, taskid, gate, gidx);
    k3_weights<<<1024, 256, 0, stream>>>(W, ldown, lup, gate, gidx, Wb0, Wb1);
    k4_gemm<<<1024, 256, 0, stream>>>(inB, Wb0, Wb1, out);
}

// Round 6
// 102.437 us; speedup vs baseline: 2.7979x; 1.0298x over previous
//
#include <hip/hip_runtime.h>
#include <hip/hip_bf16.h>

typedef __attribute__((ext_vector_type(8))) __bf16 bf16x8;
typedef __attribute__((ext_vector_type(4))) __bf16 bf16x4;
typedef __attribute__((ext_vector_type(4))) float f32x4;

#define DIN 1024
#define DOUT 1024
#define BB 4
#define SS 4096
#define MROWS (BB*SS)   /* 16384 */
#define POOLN 5
#define RR 8
#define NTASKS 5
#define TOPKK 3

// ---------------- K1a: streaming colsum-partials + f32->bf16 convert ----------
__global__ __launch_bounds__(256) void k1a_stream(const float* __restrict__ in,
                                                  __bf16* __restrict__ inB,
                                                  float* __restrict__ partial) {
    const int t = threadIdx.x;
    const int b = blockIdx.x;
    const int idx0 = b * 256 + t;                        // 0..524287
    const float4* __restrict__ inv = (const float4*)in;
    bf16x4* __restrict__ outv = (bf16x4*)inB;

    float s0 = 0.f, s1 = 0.f, s2 = 0.f, s3 = 0.f;
    size_t idx = idx0;
    float4 cur = inv[idx];
#pragma unroll
    for (int it = 0; it < 8; ++it) {
        float4 nxt = cur;
        if (it < 7) nxt = inv[idx + 524288];             // prefetch next before use
        s0 += cur.x; s1 += cur.y; s2 += cur.z; s3 += cur.w;
        bf16x4 bb = { (__bf16)cur.x, (__bf16)cur.y, (__bf16)cur.z, (__bf16)cur.w };
        outv[idx] = bb;
        cur = nxt;
        idx += 524288;
    }
    float4 p = { s0, s1, s2, s3 };
    *(float4*)&partial[(size_t)b * DIN + t * 4] = p;     // coalesced float4 store
}

// ---------------- K1b: reduce partial[2048][1024] -> colsum[1024] -------------
__global__ __launch_bounds__(256) void k1b_reduce(const float* __restrict__ partial,
                                                  float* __restrict__ colsum) {
    const int tid = blockIdx.x * 256 + threadIdx.x;      // 0..8191
    const int c = tid & (DIN - 1);
    const int g = tid >> 10;                             // 0..7
    float s = 0.f;
    const int b0 = g * 256;
#pragma unroll 8
    for (int b = b0; b < b0 + 256; ++b)
        s += partial[(size_t)b * DIN + c];
    atomicAdd(&colsum[c], s);
}

// ---------------- K2: omegas -> top-k -> softmax gate ----------------
__global__ void k2_gate(const float* __restrict__ colsum,
                        const float* __restrict__ lroute,
                        const int* __restrict__ task_id_p,
                        float* __restrict__ gate, int* __restrict__ gidx) {
    const int l = threadIdx.x;  // 64 lanes
    float part[POOLN] = {0.f, 0.f, 0.f, 0.f, 0.f};
    for (int d = l; d < DIN; d += 64) {
        const float cs = colsum[d] * (1.0f / (float)MROWS);
        const float* rp = &lroute[(size_t)1 * DIN * POOLN + (size_t)d * POOLN];
#pragma unroll
        for (int p = 0; p < POOLN; ++p) part[p] += cs * rp[p];
    }
#pragma unroll
    for (int p = 0; p < POOLN; ++p) {
        float v = part[p];
        for (int off = 32; off; off >>= 1) v += __shfl_down(v, off);
        part[p] = v;
    }
    if (l == 0) {
        int tid = *task_id_p;
        if (tid > NTASKS) tid = NTASKS;
        int L = tid < (POOLN - 1) ? tid : (POOLN - 1);   // slice [1:tid+1] clamps
        int k = tid < TOPKK ? tid : TOPKK;
        float sl[POOLN];
        for (int j = 0; j < L; ++j) sl[j] = part[1 + j];
        float G[TOPKK]; int I[TOPKK];
        int used = 0;
        for (int j = 0; j < k; ++j) {
            int best = -1; float bv = 0.f;
            for (int i2 = 0; i2 < L; ++i2) {
                if (used & (1 << i2)) continue;
                if (best < 0 || sl[i2] > bv) { bv = sl[i2]; best = i2; }
            }
            used |= 1 << best; G[j] = bv; I[j] = best;
        }
        if (k > 0) {
            float m = G[0];           // descending -> max first
            float e[TOPKK]; float se = 0.f;
            for (int j = 0; j < k; ++j) { e[j] = expf(G[j] - m); se += e[j]; }
            for (int j = 0; j < k; ++j) { gate[j] = e[j] / se; gidx[j] = I[j]; }
        }
        for (int j = k; j < TOPKK; ++j) { gate[j] = 0.f; gidx[j] = 0; }
    }
}

// ---------------- K3: build two bf16 B^T weight matrices ----------------
__global__ __launch_bounds__(256) void k3_weights(const float* __restrict__ W,
                                                  const float* __restrict__ ldown,
                                                  const float* __restrict__ lup,
                                                  const float* __restrict__ gate,
                                                  const int* __restrict__ gidx,
                                                  __bf16* __restrict__ Wb0,
                                                  __bf16* __restrict__ Wb1) {
    const int o = blockIdx.x;
    const int t = threadIdx.x;
    float c[TOPKK][RR];
#pragma unroll
    for (int j = 0; j < TOPKK; ++j) {
        const float g = gate[j];
        const int   p = gidx[j];
#pragma unroll
        for (int r = 0; r < RR; ++r)
            c[j][r] = g * lup[(size_t)p * RR * DOUT + (size_t)r * DOUT + o];
    }
    const int d0 = t * 4;
    const float4 wv = *(const float4*)&W[(size_t)o * DIN + d0];
    float outv[4] = { wv.x, wv.y, wv.z, wv.w };
    float dwv[4]  = { 0.f, 0.f, 0.f, 0.f };
#pragma unroll
    for (int j = 0; j < TOPKK; ++j) {
        const int p = gidx[j];
#pragma unroll
        for (int dd = 0; dd < 4; ++dd) {
            const float4 da = *(const float4*)&ldown[(size_t)p * DIN * RR + (size_t)(d0 + dd) * RR];
            const float4 db = *(const float4*)&ldown[(size_t)p * DIN * RR + (size_t)(d0 + dd) * RR + 4];
            dwv[dd] += da.x * c[j][0] + da.y * c[j][1] + da.z * c[j][2] + da.w * c[j][3]
                     + db.x * c[j][4] + db.y * c[j][5] + db.z * c[j][6] + db.w * c[j][7];
        }
    }
    bf16x4 b0 = { (__bf16)outv[0], (__bf16)outv[1], (__bf16)outv[2], (__bf16)outv[3] };
    bf16x4 b1 = { (__bf16)(outv[0] + dwv[0]), (__bf16)(outv[1] + dwv[1]),
                  (__bf16)(outv[2] + dwv[2]), (__bf16)(outv[3] + dwv[3]) };
    *(bf16x4*)&Wb0[(size_t)o * DIN + d0] = b0;
    *(bf16x4*)&Wb1[(size_t)o * DIN + d0] = b1;
}

// ---------------- K4: 256x256 bf16 MFMA GEMM, 4-slab pipelined, counted vmcnt --
// 8 waves (2M x 4N), wave tile 128x64. K split into 32 slabs of K=32.
// LDS = 4 slabs x (A 16KB + B 16KB) = 128 KB; prefetch depth 3; per step:
//   stage(s+3) -> vmcnt(12) -> s_barrier -> 12 ds_read_b128 + 32 MFMA -> s_barrier
// Slab layout: [rowpair 0..127][slot 0..7] of 16B units, slot = (c+4*(row&1)) ^ (rp&7)
// -> reader ds_read_b128 is 2-way-conflict-free (free per m136); staging applies the
// inverse permutation to the per-lane GLOBAL address so global_load_lds's linear
// lane->LDS mapping lands units in swizzled slots (both-sides-or-neither rule).
__global__ __launch_bounds__(512) void k4_gemm(const __bf16* __restrict__ A,
                                               const __bf16* __restrict__ B0,
                                               const __bf16* __restrict__ B1,
                                               float* __restrict__ C) {
    __shared__ ushort lds[65536];              // 128 KB; slab p at p*16384 ushorts
    const int bid = blockIdx.x;                // 0..255
    const int xcd = bid & 7;
    const int idx = bid >> 3;                  // 0..31
    const int tm  = xcd * 8 + (idx >> 2);      // 0..63 ; same-XCD blocks share A-panels
    const int tn  = idx & 3;                   // 0..3
    const __bf16* __restrict__ Bt = (tm >= 32) ? B1 : B0;   // rows >= 8192 get +delta

    const int lane = threadIdx.x & 63;
    const int wid  = threadIdx.x >> 6;         // 0..7
    const int wm = wid >> 2, wn = wid & 3;

    // ---- staging lane geometry: within a 16-row group, unit l holds (row,c):
    const int rpl  = lane >> 3;                // local rowpair 0..7
    const int sl   = (lane & 7) ^ rpl;         // logical c + 4*parity
    const int srow = rpl * 2 + (sl >> 2);      // 0..15
    const int sc   = sl & 3;                   // 16B k-chunk

    const char* gA = (const char*)A  + ((size_t)(tm*256 + wid*32 + srow)) * 2048 + sc * 16;
    const char* gB = (const char*)Bt + ((size_t)(tn*256 + wid*32 + srow)) * 2048 + sc * 16;
    const int ldsAst = wid * 1024;             // ushort idx; + p*16384 + j*512
    const int ldsBst = 8192 + wid * 1024;

    // ---- reader lane geometry (lane-constant slot; verified 2-way bank spread):
    const int rhalf = (lane & 15) >> 1;
    const int slot  = ((lane >> 4) + 4 * (lane & 1)) ^ rhalf;
    const int aoff  = (wm * 64 + rhalf) * 64 + slot * 8;          // + p*16384 + mi*512
    const int boff  = 8192 + (wn * 32 + rhalf) * 64 + slot * 8;   // + p*16384 + ni*512

    f32x4 acc[8][4];
#pragma unroll
    for (int i = 0; i < 8; ++i)
#pragma unroll
        for (int j = 0; j < 4; ++j) acc[i][j] = (f32x4){0.f, 0.f, 0.f, 0.f};

    auto stageSlab = [&](int s) {
        const int p = s & 3;
        const size_t kb = (size_t)s * 64;      // 32 bf16 = 64 B per k-slab
#pragma unroll
        for (int j = 0; j < 2; ++j) {          // two 16-row groups per wave
            __builtin_amdgcn_global_load_lds(
                (const __attribute__((address_space(1))) void*)(gA + (size_t)j * 32768 + kb),
                (__attribute__((address_space(3))) void*)&lds[p * 16384 + ldsAst + j * 512],
                16, 0, 0);
            __builtin_amdgcn_global_load_lds(
                (const __attribute__((address_space(1))) void*)(gB + (size_t)j * 32768 + kb),
                (__attribute__((address_space(3))) void*)&lds[p * 16384 + ldsBst + j * 512],
                16, 0, 0);
        }
    };

    auto computeSlab = [&](int s) {
        const int p = s & 3;
        const ushort* aB = &lds[p * 16384 + aoff];
        const ushort* bB = &lds[p * 16384 + boff];
        bf16x8 a[8], b[4];
#pragma unroll
        for (int mi = 0; mi < 8; ++mi) a[mi] = *(const bf16x8*)(aB + mi * 512);
#pragma unroll
        for (int ni = 0; ni < 4; ++ni) b[ni] = *(const bf16x8*)(bB + ni * 512);
        __builtin_amdgcn_s_setprio(1);
#pragma unroll
        for (int mi = 0; mi < 8; ++mi)
#pragma unroll
            for (int ni = 0; ni < 4; ++ni)
                acc[mi][ni] = __builtin_amdgcn_mfma_f32_16x16x32_bf16(
                    a[mi], b[ni], acc[mi][ni], 0, 0, 0);
        __builtin_amdgcn_s_setprio(0);
    };

    // prologue: 3 slabs in flight
    stageSlab(0); stageSlab(1); stageSlab(2);

#define K4_STEP(S, NSTR, DOSTAGE)                                     \
    {                                                                 \
        if (DOSTAGE) stageSlab((S) + 3);                              \
        asm volatile("s_waitcnt vmcnt(" NSTR ")" ::: "memory");       \
        __builtin_amdgcn_s_barrier();                                 \
        asm volatile("" ::: "memory");                                \
        computeSlab(S);                                               \
        asm volatile("" ::: "memory");                                \
        __builtin_amdgcn_s_barrier();                                 \
    }

#pragma unroll 1
    for (int s = 0; s < 29; ++s) K4_STEP(s, "12", true);
    K4_STEP(29, "8", false);
    K4_STEP(30, "4", false);
    K4_STEP(31, "0", false);
#undef K4_STEP

    // epilogue: D col = lane&15, row = (lane>>4)*4 + r
#pragma unroll
    for (int mi = 0; mi < 8; ++mi) {
#pragma unroll
        for (int r = 0; r < 4; ++r) {
            const int grow = tm * 256 + wm * 128 + mi * 16 + (lane >> 4) * 4 + r;
            float* cp = C + (size_t)grow * 1024 + tn * 256 + wn * 64 + (lane & 15);
#pragma unroll
            for (int ni = 0; ni < 4; ++ni) cp[ni * 16] = acc[mi][ni][r];
        }
    }
}

extern "C" void kernel_launch(void* const* d_in, const int* in_sizes, int n_in,
                              void* d_out, int out_size, void* d_ws, size_t ws_size,
                              hipStream_t stream) {
    const float* in     = (const float*)d_in[0];
    const float* W      = (const float*)d_in[1];
    const float* ldown  = (const float*)d_in[2];
    const float* lup    = (const float*)d_in[3];
    const float* lroute = (const float*)d_in[4];
    const int*   taskid = (const int*)d_in[5];
    float* out = (float*)d_out;

    // workspace carve (~36.6 MB)
    __bf16* inB   = (__bf16*)d_ws;                              // 32 MB
    __bf16* Wb0   = inB + (size_t)MROWS * DIN;                  // 2 MB
    __bf16* Wb1   = Wb0 + (size_t)DOUT * DIN;                   // 2 MB
    float*  colsum= (float*)(Wb1 + (size_t)DOUT * DIN);         // 4 KB
    float*  gate  = colsum + DIN;
    int*    gidx  = (int*)(gate + TOPKK);

    // partial colsums live in d_out (8 MB of its 64 MB) — k4 fully overwrites
    // d_out afterwards, so this is deterministic and costs no workspace.
    float* partial = out;

    hipMemsetAsync(colsum, 0, DIN * sizeof(float), stream);
    k1a_stream<<<2048, 256, 0, stream>>>(in, inB, partial);
    k1b_reduce<<<32, 256, 0, stream>>>(partial, colsum);
    k2_gate<<<1, 64, 0, stream>>>(colsum, lroute, taskid, gate, gidx);
    k3_weights<<<1024, 256, 0, stream>>>(W, ldown, lup, gate, gidx, Wb0, Wb1);
    k4_gemm<<<256, 512, 0, stream>>>(inB, Wb0, Wb1, out);
}